// Round 3
// baseline (2829.697 us; speedup 1.0000x reference)
//
#include <hip/hip_runtime.h>
#include <stdint.h>

#define NROWS 32768
#define KP    4000
#define DIM   128
#define CL    1000
#define NCHUNKS 4
#define KCHUNK  (KP / NCHUNKS)     // 1000

// Map float to u32 with same total order (handles negatives).
__device__ __forceinline__ unsigned int f2ord(float f) {
    unsigned int u = __float_as_uint(f);
    return (u & 0x80000000u) ? ~u : (u | 0x80000000u);
}

// p2[k] = ||proxies[k]||^2 ; packed[n] init to u64 max (ws is poisoned)
__global__ void init_kernel(unsigned long long* __restrict__ packed,
                            float* __restrict__ p2,
                            const float* __restrict__ proxies) {
    int i = blockIdx.x * blockDim.x + threadIdx.x;
    if (i < NROWS) packed[i] = 0xFFFFFFFFFFFFFFFFull;
    if (i < KP) {
        const float4* p = (const float4*)(proxies + (long)i * DIM);
        float s = 0.f;
        #pragma unroll
        for (int d = 0; d < DIM / 4; d++) {
            float4 v = p[d];
            s = fmaf(v.x, v.x, s); s = fmaf(v.y, v.y, s);
            s = fmaf(v.z, v.z, s); s = fmaf(v.w, v.w, s);
        }
        p2[i] = s;
    }
}

// 16 FMAs against one float4 quad group.
#define DOT4(acc, xv, pv)                                   \
    acc = fmaf((xv).x, (pv).x, acc);                        \
    acc = fmaf((xv).y, (pv).y, acc);                        \
    acc = fmaf((xv).z, (pv).z, acc);                        \
    acc = fmaf((xv).w, (pv).w, acc);

// 1 thread per row; full 128-float x row resident in VGPRs
// (__launch_bounds__(256,2) -> 256-VGPR budget). Proxy rows are
// wave-uniform loads, ping-pong prefetched (A/B) so L1/L2 latency hides
// under the 128 FMAs of the other row. score = p2[k] - 2*dot.
__global__ void __launch_bounds__(256, 2)
argmin_kernel(const float* __restrict__ x,
              const float* __restrict__ proxies,
              const float* __restrict__ p2,
              unsigned long long* __restrict__ packed) {
    const int row = blockIdx.x * 256 + threadIdx.x;   // grid.x = 128
    const int k0  = blockIdx.y * KCHUNK;              // grid.y = 4

    // x row -> 32 float4 = 128 VGPRs
    float4 xr[32];
    const float4* xp = (const float4*)(x + (long)row * DIM);
    #pragma unroll
    for (int i = 0; i < 32; i++) xr[i] = xp[i];

    float best = 3.4e38f;
    int bestk = k0;

    // prime buffer A with row k0 (wave-uniform address)
    float4 pa[8], pb[8];
    const float4* pk0 = (const float4*)(proxies + (long)k0 * DIM);

    for (int half = 0; half < 2; half++) {   // 2 half-rows of 16 float4? no:
        // (kept trivial: full row in 8-reg slices below)
        break;
    }

    // We process each proxy row in 4 slices of 8 float4 to bound live regs:
    // slice s covers dims [s*32, s*32+32). Prefetch next k's slice while
    // computing current slice -> software pipeline across k.
    // Layout: for k: dot = sum over 4 slices.
    const int kend = k0 + KCHUNK;

    // ---- software pipeline over k, 2-deep (A computes, B prefetches) ----
    // load full row k0 into A (32 float4 worth via 4 slices of 8)
    float4 A0[8], A1[8], A2[8], A3[8];
    {
        const float4* p = pk0;
        #pragma unroll
        for (int i = 0; i < 8; i++) A0[i] = p[i];
        #pragma unroll
        for (int i = 0; i < 8; i++) A1[i] = p[8 + i];
        #pragma unroll
        for (int i = 0; i < 8; i++) A2[i] = p[16 + i];
        #pragma unroll
        for (int i = 0; i < 8; i++) A3[i] = p[24 + i];
    }

    for (int k = k0; k < kend; k += 2) {
        // prefetch row k+1 into B
        float4 B0[8], B1[8], B2[8], B3[8];
        {
            const float4* p = (const float4*)(proxies + (long)(k + 1) * DIM);
            #pragma unroll
            for (int i = 0; i < 8; i++) B0[i] = p[i];
            #pragma unroll
            for (int i = 0; i < 8; i++) B1[i] = p[8 + i];
            #pragma unroll
            for (int i = 0; i < 8; i++) B2[i] = p[16 + i];
            #pragma unroll
            for (int i = 0; i < 8; i++) B3[i] = p[24 + i];
        }
        // compute row k from A
        {
            float a0 = 0.f, a1 = 0.f, a2 = 0.f, a3 = 0.f;
            #pragma unroll
            for (int i = 0; i < 8; i++) { DOT4(a0, xr[i],      A0[i]); }
            #pragma unroll
            for (int i = 0; i < 8; i++) { DOT4(a1, xr[8 + i],  A1[i]); }
            #pragma unroll
            for (int i = 0; i < 8; i++) { DOT4(a2, xr[16 + i], A2[i]); }
            #pragma unroll
            for (int i = 0; i < 8; i++) { DOT4(a3, xr[24 + i], A3[i]); }
            float dot = (a0 + a1) + (a2 + a3);
            float score = fmaf(-2.f, dot, p2[k]);
            if (score < best) { best = score; bestk = k; }
        }
        // prefetch row k+2 into A (guarded: stays within this chunk)
        if (k + 2 < kend) {
            const float4* p = (const float4*)(proxies + (long)(k + 2) * DIM);
            #pragma unroll
            for (int i = 0; i < 8; i++) A0[i] = p[i];
            #pragma unroll
            for (int i = 0; i < 8; i++) A1[i] = p[8 + i];
            #pragma unroll
            for (int i = 0; i < 8; i++) A2[i] = p[16 + i];
            #pragma unroll
            for (int i = 0; i < 8; i++) A3[i] = p[24 + i];
        }
        // compute row k+1 from B
        {
            float a0 = 0.f, a1 = 0.f, a2 = 0.f, a3 = 0.f;
            #pragma unroll
            for (int i = 0; i < 8; i++) { DOT4(a0, xr[i],      B0[i]); }
            #pragma unroll
            for (int i = 0; i < 8; i++) { DOT4(a1, xr[8 + i],  B1[i]); }
            #pragma unroll
            for (int i = 0; i < 8; i++) { DOT4(a2, xr[16 + i], B2[i]); }
            #pragma unroll
            for (int i = 0; i < 8; i++) { DOT4(a3, xr[24 + i], B3[i]); }
            float dot = (a0 + a1) + (a2 + a3);
            float score = fmaf(-2.f, dot, p2[k + 1]);
            if (score < best) { best = score; bestk = k + 1; }
        }
    }

    unsigned long long key =
        ((unsigned long long)f2ord(best) << 32) | (unsigned int)bestk;
    atomicMin(&packed[row], key);   // ties -> smaller k (strict < above)
}

// Fused epilogue: out = [x | proxies[idx] | labels[idx]] as one stream.
__global__ void out_kernel(const float4* __restrict__ x4,
                           const float4* __restrict__ prox4,
                           const float4* __restrict__ lab4,
                           const unsigned long long* __restrict__ packed,
                           float4* __restrict__ out4) {
    const int R0 = NROWS * (DIM / 4);           // 1,048,576
    const int R1 = 2 * NROWS * (DIM / 4);       // 2,097,152
    const int TOT = R1 + NROWS * (CL / 4);      // 10,289,152
    for (int j = blockIdx.x * blockDim.x + threadIdx.x; j < TOT;
         j += gridDim.x * blockDim.x) {
        if (j < R0) {
            out4[j] = x4[j];
        } else if (j < R1) {
            int m = j - R0;
            int n = m >> 5, d = m & 31;
            int k = (int)(unsigned int)(packed[n] & 0xFFFFFFFFull);
            out4[j] = prox4[(long)k * (DIM / 4) + d];
        } else {
            int m = j - R1;
            int n = m / (CL / 4), d = m % (CL / 4);
            int k = (int)(unsigned int)(packed[n] & 0xFFFFFFFFull);
            out4[j] = lab4[(long)k * (CL / 4) + d];
        }
    }
}

extern "C" void kernel_launch(void* const* d_in, const int* in_sizes, int n_in,
                              void* d_out, int out_size, void* d_ws, size_t ws_size,
                              hipStream_t stream) {
    const float* x       = (const float*)d_in[0];
    const float* proxies = (const float*)d_in[1];
    const float* labels  = (const float*)d_in[2];
    float* out = (float*)d_out;

    float* p2 = (float*)d_ws;                                       // 4000 f
    unsigned long long* packed =
        (unsigned long long*)((char*)d_ws + 16384);                 // 32768 u64

    init_kernel<<<dim3(NROWS / 256), dim3(256), 0, stream>>>(packed, p2, proxies);

    dim3 g(NROWS / 256, NCHUNKS);   // 128 x 4 = 512 blocks = 2/CU exactly
    argmin_kernel<<<g, dim3(256), 0, stream>>>(x, proxies, p2, packed);

    out_kernel<<<dim3(2048), dim3(256), 0, stream>>>(
        (const float4*)x, (const float4*)proxies, (const float4*)labels,
        packed, (float4*)out);
}